// Round 6
// baseline (115.697 us; speedup 1.0000x reference)
//
#include <hip/hip_runtime.h>

#define NSITES 784
#define BS_TOT 16384
#define WPB 16      // samples per block
#define KSEG 16     // segments per sample
#define GSEG 49     // sites per segment (16*49 = 784)

// Raw site tensor in 8 float4s c0..c7:
//   c{2l}   = (T[l][0][0], T[l][0][1], T[l][1][0], T[l][1][1])
//   c{2l+1} = (T[l][2][0], T[l][2][1], T[l][3][0], T[l][3][1])
// SELROW: row l of selected matrix M[l][r] = T[l][r][p]; bit=1 -> x=1 -> p=0 -> .x/.z lanes
#define SELROW(dst, bitset, ra, rb) \
  dst = (bitset) ? make_float4(ra.x, ra.z, rb.x, rb.z) : make_float4(ra.y, ra.w, rb.y, rb.w)

// Q_row = P_row * M (rows of M in m0..m3)
#define MM_ROW(Q, Pr) do { \
  Q.x = fmaf(Pr.x, m0.x, fmaf(Pr.y, m1.x, fmaf(Pr.z, m2.x, Pr.w * m3.x))); \
  Q.y = fmaf(Pr.x, m0.y, fmaf(Pr.y, m1.y, fmaf(Pr.z, m2.y, Pr.w * m3.y))); \
  Q.z = fmaf(Pr.x, m0.z, fmaf(Pr.y, m1.z, fmaf(Pr.z, m2.z, Pr.w * m3.z))); \
  Q.w = fmaf(Pr.x, m0.w, fmaf(Pr.y, m1.w, fmaf(Pr.z, m2.w, Pr.w * m3.w))); \
} while (0)

#define LOAD8(r0,r1,r2,r3,r4,r5,r6,r7, src) do { const float4* f4_ = (const float4*)(src); \
  r0 = f4_[0]; r1 = f4_[1]; r2 = f4_[2]; r3 = f4_[3]; \
  r4 = f4_[4]; r5 = f4_[5]; r6 = f4_[6]; r7 = f4_[7]; } while (0)

// P (P0..P3) <- P * M(selected from raw regs c0..c7 by bit)
#define MMSTEP(bitset, c0,c1,c2,c3,c4,c5,c6,c7) do { \
  float4 m0, m1, m2, m3; \
  SELROW(m0, bitset, c0, c1); \
  SELROW(m1, bitset, c2, c3); \
  SELROW(m2, bitset, c4, c5); \
  SELROW(m3, bitset, c6, c7); \
  float4 Q0, Q1, Q2, Q3; \
  MM_ROW(Q0, P0); MM_ROW(Q1, P1); MM_ROW(Q2, P2); MM_ROW(Q3, P3); \
  P0 = Q0; P1 = Q1; P2 = Q2; P3 = Q3; \
} while (0)

// Round-0-verified STEP on raw registers c0..c7.
// t_[l*8+r*2+p]: p00 uses t_[0],t_[8],t_[16],t_[24] = c0.x,c2.x,c4.x,c6.x etc.
#define STEP_REG(bitset, c0,c1,c2,c3,c4,c5,c6,c7) do { \
  float p00 = fmaf(left0, c0.x, fmaf(left1, c2.x, fmaf(left2, c4.x, left3 * c6.x))); \
  float p01 = fmaf(left0, c0.y, fmaf(left1, c2.y, fmaf(left2, c4.y, left3 * c6.y))); \
  float p10 = fmaf(left0, c0.z, fmaf(left1, c2.z, fmaf(left2, c4.z, left3 * c6.z))); \
  float p11 = fmaf(left0, c0.w, fmaf(left1, c2.w, fmaf(left2, c4.w, left3 * c6.w))); \
  float p20 = fmaf(left0, c1.x, fmaf(left1, c3.x, fmaf(left2, c5.x, left3 * c7.x))); \
  float p21 = fmaf(left0, c1.y, fmaf(left1, c3.y, fmaf(left2, c5.y, left3 * c7.y))); \
  float p30 = fmaf(left0, c1.z, fmaf(left1, c3.z, fmaf(left2, c5.z, left3 * c7.z))); \
  float p31 = fmaf(left0, c1.w, fmaf(left1, c3.w, fmaf(left2, c5.w, left3 * c7.w))); \
  bool s_ = (bitset); \
  float mx_ = fmaxf(p00, p01); \
  float ch_ = s_ ? p00 : p01; \
  acc_nat += (ch_ - mx_); \
  float ad_ = fabsf(p00 - p01); \
  acc_l2 += __builtin_amdgcn_logf(1.0f + __builtin_amdgcn_exp2f(-ad_ * 1.4426950408889634f)); \
  left0 = s_ ? p00 : p01; \
  left1 = s_ ? p10 : p11; \
  left2 = s_ ? p20 : p21; \
  left3 = s_ ? p30 : p31; \
} while (0)

__global__ __launch_bounds__(256, 4) void amps_mega(
    const float* __restrict__ data,      // (BS, 784) in {0,1}
    const float* __restrict__ tensors,   // (784, 4, 4, 2)
    float* __restrict__ out)             // (BS,)
{
    __shared__ unsigned long long sPacked[WPB][14];          // 13 words used, pad to 14
    __shared__ __align__(16) float sP[KSEG][WPB][16];        // segment products (rows)
    __shared__ __align__(16) float sPre[KSEG][WPB][4];       // prefix left vectors
    __shared__ float sRes[KSEG][WPB];                        // per-segment partial logprob

    const int t  = threadIdx.x;
    const int s0 = blockIdx.x * WPB;

    // ---------- in-kernel pack: wave wv ballots rows 4*wv .. 4*wv+3 ----------
    {
        const int wv = t >> 6, lane = t & 63;
        #pragma unroll
        for (int rr = 0; rr < 4; ++rr) {
            const int r = wv * 4 + rr;
            const float* row = data + (size_t)(s0 + r) * NSITES;
            float v[12];
            #pragma unroll
            for (int w = 0; w < 12; ++w) v[w] = row[w * 64 + lane];
            float vt = (lane < 16) ? row[768 + lane] : 0.0f;   // guard: no OOB read
            #pragma unroll
            for (int w = 0; w < 12; ++w) {
                unsigned long long m = __ballot(v[w] == 1.0f);
                if (lane == 0) sPacked[r][w] = m;
            }
            unsigned long long mt = __ballot(vt == 1.0f);
            if (lane == 0) sPacked[r][12] = mt;
        }
    }
    __syncthreads();

    const int k  = t >> 4;       // segment (wave-quasi-uniform: 4 distinct k per wave)
    const int s  = t & 15;       // sample-in-block
    const int n0 = k * GSEG;
    unsigned long long win;
    {
        const int a0 = n0 >> 6, sh = n0 & 63;
        unsigned long long w0 = sPacked[s][a0];
        unsigned long long w1 = sPacked[s][a0 + 1];
        win = sh ? ((w0 >> sh) | (w1 << (64 - sh))) : w0;
    }
    const float* tb = tensors + (size_t)n0 * 32;

    // ---------- phase A: segment product P_k (last segment's product unused) ----------
    if (k < KSEG - 1) {
        float4 P0, P1, P2, P3;
        float4 a0, a1, a2, a3, a4, a5, a6, a7;
        LOAD8(a0,a1,a2,a3,a4,a5,a6,a7, tb);                       // site n0
        SELROW(P0, (win & 1ull), a0, a1);
        SELROW(P1, (win & 1ull), a2, a3);
        SELROW(P2, (win & 1ull), a4, a5);
        SELROW(P3, (win & 1ull), a6, a7);
        LOAD8(a0,a1,a2,a3,a4,a5,a6,a7, tb + 32);                  // site n0+1
        #pragma unroll 1
        for (int i = 1; i < GSEG - 1; i += 2) {   // sites 1..48, two per iter
            float4 b0, b1, b2, b3, b4, b5, b6, b7;
            LOAD8(b0,b1,b2,b3,b4,b5,b6,b7, tb + (size_t)(i + 1) * 32);
            MMSTEP(((win >> i) & 1ull), a0,a1,a2,a3,a4,a5,a6,a7);
            const int i2 = (i + 2 <= GSEG - 1) ? (i + 2) : (GSEG - 1);
            LOAD8(a0,a1,a2,a3,a4,a5,a6,a7, tb + (size_t)i2 * 32);
            MMSTEP(((win >> (i + 1)) & 1ull), b0,b1,b2,b3,b4,b5,b6,b7);
        }
        float4* dst = (float4*)sP[k][s];
        dst[0] = P0; dst[1] = P1; dst[2] = P2; dst[3] = P3;
    }
    __syncthreads();

    // ---------- phase B: serial prefix scan per sample (16 owner threads) ----------
    if (t < WPB) {
        float l0 = 1.0f, l1 = 0.0f, l2 = 0.0f, l3 = 0.0f;
        #pragma unroll
        for (int kk = 0; kk < KSEG; ++kk) {
            *(float4*)sPre[kk][t] = make_float4(l0, l1, l2, l3);
            if (kk < KSEG - 1) {
                const float4* q = (const float4*)sP[kk][t];
                float4 q0 = q[0], q1 = q[1], q2 = q[2], q3 = q[3];
                float m0_ = fmaf(l0, q0.x, fmaf(l1, q1.x, fmaf(l2, q2.x, l3 * q3.x)));
                float m1_ = fmaf(l0, q0.y, fmaf(l1, q1.y, fmaf(l2, q2.y, l3 * q3.y)));
                float m2_ = fmaf(l0, q0.z, fmaf(l1, q1.z, fmaf(l2, q2.z, l3 * q3.z)));
                float m3_ = fmaf(l0, q0.w, fmaf(l1, q1.w, fmaf(l2, q2.w, l3 * q3.w)));
                l0 = m0_; l1 = m1_; l2 = m2_; l3 = m3_;
            }
        }
    }
    __syncthreads();

    // ---------- phase C: log-softmax walk over own segment ----------
    {
        const float4 pre = *(const float4*)sPre[k][s];
        float left0 = pre.x, left1 = pre.y, left2 = pre.z, left3 = pre.w;
        float acc_nat = 0.0f, acc_l2 = 0.0f;
        float4 a0, a1, a2, a3, a4, a5, a6, a7;
        LOAD8(a0,a1,a2,a3,a4,a5,a6,a7, tb);                       // site n0
        #pragma unroll 1
        for (int i = 0; i < GSEG - 1; i += 2) {   // sites 0..47, two per iter
            float4 b0, b1, b2, b3, b4, b5, b6, b7;
            LOAD8(b0,b1,b2,b3,b4,b5,b6,b7, tb + (size_t)(i + 1) * 32);
            STEP_REG(((win >> i) & 1ull), a0,a1,a2,a3,a4,a5,a6,a7);
            const int i2 = (i + 2 <= GSEG - 1) ? (i + 2) : (GSEG - 1);
            LOAD8(a0,a1,a2,a3,a4,a5,a6,a7, tb + (size_t)i2 * 32);
            STEP_REG(((win >> (i + 1)) & 1ull), b0,b1,b2,b3,b4,b5,b6,b7);
        }
        STEP_REG(((win >> (GSEG - 1)) & 1ull), a0,a1,a2,a3,a4,a5,a6,a7);  // site n0+48
        sRes[k][s] = acc_nat - 0.6931471805599453f * acc_l2;
    }
    __syncthreads();

    // ---------- phase D: reduce K partials per sample ----------
    if (t < WPB) {
        float acc = 0.0f;
        #pragma unroll
        for (int kk = 0; kk < KSEG; ++kk) acc += sRes[kk][t];
        out[s0 + t] = acc;
    }
}

extern "C" void kernel_launch(void* const* d_in, const int* in_sizes, int n_in,
                              void* d_out, int out_size, void* d_ws, size_t ws_size,
                              hipStream_t stream) {
    const float* data    = (const float*)d_in[0];   // (16384, 784) float32
    const float* tensors = (const float*)d_in[1];   // (784, 4, 4, 2) float32
    float* out = (float*)d_out;                     // (16384,) float32

    hipLaunchKernelGGL(amps_mega, dim3(BS_TOT / WPB), dim3(256), 0, stream,
                       data, tensors, out);
}

// Round 7
// 97.751 us; speedup vs baseline: 1.1836x; 1.1836x over previous
//
#include <hip/hip_runtime.h>

#define NSITES 784
#define BS_TOT 16384
#define WPB 64      // samples per block (= lanes per wave)
#define KSEG 16     // segments per sample (= waves per block)
#define GSEG 49     // sites per segment (16*49 = 784)

// ---------------- per-site step (round-0 verified, absmax 0) ----------------
// t_ points at site tensor (32 floats, layout [l][r][p], flat l*8+r*2+p).
// t_ is WAVE-UNIFORM here -> compiler emits s_load through K$; FMAs take SGPR operands.
#define STEP(sbit, TP) do {                                                          \
    const float* t_ = (TP);                                                          \
    float p00 = fmaf(left0, t_[0],  fmaf(left1, t_[8],  fmaf(left2, t_[16], left3 * t_[24]))); \
    float p01 = fmaf(left0, t_[1],  fmaf(left1, t_[9],  fmaf(left2, t_[17], left3 * t_[25]))); \
    float p10 = fmaf(left0, t_[2],  fmaf(left1, t_[10], fmaf(left2, t_[18], left3 * t_[26]))); \
    float p11 = fmaf(left0, t_[3],  fmaf(left1, t_[11], fmaf(left2, t_[19], left3 * t_[27]))); \
    float p20 = fmaf(left0, t_[4],  fmaf(left1, t_[12], fmaf(left2, t_[20], left3 * t_[28]))); \
    float p21 = fmaf(left0, t_[5],  fmaf(left1, t_[13], fmaf(left2, t_[21], left3 * t_[29]))); \
    float p30 = fmaf(left0, t_[6],  fmaf(left1, t_[14], fmaf(left2, t_[22], left3 * t_[30]))); \
    float p31 = fmaf(left0, t_[7],  fmaf(left1, t_[15], fmaf(left2, t_[23], left3 * t_[31]))); \
    bool s_ = (sbit);                                                                \
    float mx_ = fmaxf(p00, p01);                                                     \
    float ch_ = s_ ? p00 : p01;                                                      \
    acc_nat += (ch_ - mx_);                                                          \
    float ad_ = fabsf(p00 - p01);                                                    \
    acc_l2 += __builtin_amdgcn_logf(1.0f + __builtin_amdgcn_exp2f(-ad_ * 1.4426950408889634f)); \
    left0 = s_ ? p00 : p01;                                                          \
    left1 = s_ ? p10 : p11;                                                          \
    left2 = s_ ? p20 : p21;                                                          \
    left3 = s_ ? p30 : p31;                                                          \
} while (0)

__global__ __launch_bounds__(1024) void amps_mega2(
    const float* __restrict__ data,      // (BS, 784) in {0,1}
    const float* __restrict__ tensors,   // (784, 4, 4, 2)
    float* __restrict__ out)             // (BS,)
{
    // All per-sample state laid out [...][lane] (stride 4B across lanes -> conflict-free)
    __shared__ unsigned long long sPacked[WPB][15];   // 13 words used; 15 -> 4-way on reads
    __shared__ float sP[KSEG][16][WPB];               // segment products, elem e = l*4+j
    __shared__ float sPre[KSEG][4][WPB];              // prefix left vectors
    __shared__ float sRes[KSEG][WPB];                 // per-segment partial logprob

    const int t    = threadIdx.x;
    const int wv   = t >> 6;      // wave index = segment k (WAVE-UNIFORM)
    const int lane = t & 63;      // lane = sample-in-block
    const int s0   = blockIdx.x * WPB;

    // ---------- pack: wave wv ballots rows 4*wv .. 4*wv+3 (coalesced) ----------
    {
        #pragma unroll
        for (int rr = 0; rr < 4; ++rr) {
            const int r = wv * 4 + rr;
            const float* row = data + (size_t)(s0 + r) * NSITES;
            float v[12];
            #pragma unroll
            for (int w = 0; w < 12; ++w) v[w] = row[w * 64 + lane];
            float vt = (lane < 16) ? row[768 + lane] : 0.0f;
            #pragma unroll
            for (int w = 0; w < 12; ++w) {
                unsigned long long m = __ballot(v[w] == 1.0f);
                if (lane == 0) sPacked[r][w] = m;
            }
            unsigned long long mt = __ballot(vt == 1.0f);
            if (lane == 0) sPacked[r][12] = mt;
        }
    }
    __syncthreads();

    const int k  = wv;
    const int n0 = k * GSEG;
    unsigned long long win;
    {
        const int a0 = n0 >> 6, sh = n0 & 63;
        unsigned long long w0 = sPacked[lane][a0];
        unsigned long long w1 = sPacked[lane][a0 + 1];
        win = sh ? ((w0 >> sh) | (w1 << (64 - sh))) : w0;
    }
    const float* tb = tensors + (size_t)n0 * 32;   // wave-uniform

    // ---------- phase A: segment product P_k = M_{n0} * ... * M_{n0+G-1} ----------
    // (row-vector convention; k = KSEG-1 product unused)
    if (k < KSEG - 1) {
        float P[4][4];
        {
            const bool b0 = (win & 1ull) != 0;     // x==1 -> phys 0
            #pragma unroll
            for (int l = 0; l < 4; ++l)
                #pragma unroll
                for (int j = 0; j < 4; ++j)
                    P[l][j] = b0 ? tb[l * 8 + j * 2] : tb[l * 8 + j * 2 + 1];
        }
        #pragma unroll 2
        for (int i = 1; i < GSEG; ++i) {
            const float* ts = tb + i * 32;         // wave-uniform -> s_load
            const bool bi = ((win >> i) & 1ull) != 0;
            float M[4][4];
            #pragma unroll
            for (int l = 0; l < 4; ++l)
                #pragma unroll
                for (int j = 0; j < 4; ++j)
                    M[l][j] = bi ? ts[l * 8 + j * 2] : ts[l * 8 + j * 2 + 1];
            float Q[4][4];
            #pragma unroll
            for (int r = 0; r < 4; ++r)
                #pragma unroll
                for (int j = 0; j < 4; ++j)
                    Q[r][j] = fmaf(P[r][0], M[0][j], fmaf(P[r][1], M[1][j],
                              fmaf(P[r][2], M[2][j], P[r][3] * M[3][j])));
            #pragma unroll
            for (int r = 0; r < 4; ++r)
                #pragma unroll
                for (int j = 0; j < 4; ++j)
                    P[r][j] = Q[r][j];
        }
        #pragma unroll
        for (int l = 0; l < 4; ++l)
            #pragma unroll
            for (int j = 0; j < 4; ++j)
                sP[k][l * 4 + j][lane] = P[l][j];
    }
    __syncthreads();

    // ---------- phase B: serial prefix scan per sample (64 owner threads, wave 0) ----------
    if (t < WPB) {
        float l0 = 1.0f, l1 = 0.0f, l2 = 0.0f, l3 = 0.0f;
        #pragma unroll
        for (int kk = 0; kk < KSEG; ++kk) {
            sPre[kk][0][t] = l0; sPre[kk][1][t] = l1;
            sPre[kk][2][t] = l2; sPre[kk][3][t] = l3;
            if (kk < KSEG - 1) {
                float Pv[16];
                #pragma unroll
                for (int e = 0; e < 16; ++e) Pv[e] = sP[kk][e][t];
                float n0_ = fmaf(l0, Pv[0], fmaf(l1, Pv[4], fmaf(l2, Pv[8],  l3 * Pv[12])));
                float n1_ = fmaf(l0, Pv[1], fmaf(l1, Pv[5], fmaf(l2, Pv[9],  l3 * Pv[13])));
                float n2_ = fmaf(l0, Pv[2], fmaf(l1, Pv[6], fmaf(l2, Pv[10], l3 * Pv[14])));
                float n3_ = fmaf(l0, Pv[3], fmaf(l1, Pv[7], fmaf(l2, Pv[11], l3 * Pv[15])));
                l0 = n0_; l1 = n1_; l2 = n2_; l3 = n3_;
            }
        }
    }
    __syncthreads();

    // ---------- phase C: log-softmax walk over own segment (scalar tensor loads) ----------
    {
        float left0 = sPre[k][0][lane], left1 = sPre[k][1][lane];
        float left2 = sPre[k][2][lane], left3 = sPre[k][3][lane];
        float acc_nat = 0.0f, acc_l2 = 0.0f;
        #pragma unroll 2
        for (int i = 0; i < GSEG; ++i) {
            STEP(((win >> i) & 1ull) != 0, tb + i * 32);
        }
        sRes[k][lane] = acc_nat - 0.6931471805599453f * acc_l2;
    }
    __syncthreads();

    // ---------- phase D: reduce K partials per sample ----------
    if (t < WPB) {
        float acc = 0.0f;
        #pragma unroll
        for (int kk = 0; kk < KSEG; ++kk) acc += sRes[kk][t];
        out[s0 + t] = acc;
    }
}

extern "C" void kernel_launch(void* const* d_in, const int* in_sizes, int n_in,
                              void* d_out, int out_size, void* d_ws, size_t ws_size,
                              hipStream_t stream) {
    const float* data    = (const float*)d_in[0];   // (16384, 784) float32
    const float* tensors = (const float*)d_in[1];   // (784, 4, 4, 2) float32
    float* out = (float*)d_out;                     // (16384,) float32

    hipLaunchKernelGGL(amps_mega2, dim3(BS_TOT / WPB), dim3(1024), 0, stream,
                       data, tensors, out);
}

// Round 8
// 89.765 us; speedup vs baseline: 1.2889x; 1.0890x over previous
//
#include <hip/hip_runtime.h>

#define NSITES 784
#define BS_TOT 16384
#define KSEG 16
#define GSEG 49     // 16*49 = 784
#define WPB  64     // samples per scan_walk block

// ---------------- per-site step (round-0 verified, absmax 0) ----------------
// t_ -> site tensor (32 floats, layout [l][r][p], flat l*8+r*2+p). Wave-uniform -> s_load.
#define STEP(sbit, TP) do {                                                          \
    const float* t_ = (TP);                                                          \
    float p00 = fmaf(left0, t_[0],  fmaf(left1, t_[8],  fmaf(left2, t_[16], left3 * t_[24]))); \
    float p01 = fmaf(left0, t_[1],  fmaf(left1, t_[9],  fmaf(left2, t_[17], left3 * t_[25]))); \
    float p10 = fmaf(left0, t_[2],  fmaf(left1, t_[10], fmaf(left2, t_[18], left3 * t_[26]))); \
    float p11 = fmaf(left0, t_[3],  fmaf(left1, t_[11], fmaf(left2, t_[19], left3 * t_[27]))); \
    float p20 = fmaf(left0, t_[4],  fmaf(left1, t_[12], fmaf(left2, t_[20], left3 * t_[28]))); \
    float p21 = fmaf(left0, t_[5],  fmaf(left1, t_[13], fmaf(left2, t_[21], left3 * t_[29]))); \
    float p30 = fmaf(left0, t_[6],  fmaf(left1, t_[14], fmaf(left2, t_[22], left3 * t_[30]))); \
    float p31 = fmaf(left0, t_[7],  fmaf(left1, t_[15], fmaf(left2, t_[23], left3 * t_[31]))); \
    bool s_ = (sbit);                                                                \
    float mx_ = fmaxf(p00, p01);                                                     \
    float ch_ = s_ ? p00 : p01;                                                      \
    acc_nat += (ch_ - mx_);                                                          \
    float ad_ = fabsf(p00 - p01);                                                    \
    acc_l2 += __builtin_amdgcn_logf(1.0f + __builtin_amdgcn_exp2f(-ad_ * 1.4426950408889634f)); \
    left0 = s_ ? p00 : p01;                                                          \
    left1 = s_ ? p10 : p11;                                                          \
    left2 = s_ ? p20 : p21;                                                          \
    left3 = s_ ? p30 : p31;                                                          \
} while (0)

// Q_row = P_row * M  (rows of M in float4 m0..m3)
#define MM_ROW(Q, Pr) do {                                                           \
    Q.x = fmaf(Pr.x, m0.x, fmaf(Pr.y, m1.x, fmaf(Pr.z, m2.x, Pr.w * m3.x)));         \
    Q.y = fmaf(Pr.x, m0.y, fmaf(Pr.y, m1.y, fmaf(Pr.z, m2.y, Pr.w * m3.y)));         \
    Q.z = fmaf(Pr.x, m0.z, fmaf(Pr.y, m1.z, fmaf(Pr.z, m2.z, Pr.w * m3.z)));         \
    Q.w = fmaf(Pr.x, m0.w, fmaf(Pr.y, m1.w, fmaf(Pr.z, m2.w, Pr.w * m3.w)));         \
} while (0)

// ================= kernel 1: pack data bits (coalesced + ballot) =================
__global__ __launch_bounds__(256) void pack_kernel(const float* __restrict__ data,
                                                   unsigned long long* __restrict__ packed) {
    int gid  = blockIdx.x * 256 + threadIdx.x;
    int row  = gid >> 6;
    int lane = threadIdx.x & 63;
    const float* r = data + (size_t)row * NSITES;
    #pragma unroll
    for (int w = 0; w < 12; ++w) {
        unsigned long long m = __ballot(r[w * 64 + lane] == 1.0f);
        if (lane == 0) packed[(size_t)w * BS_TOT + row] = m;
    }
    float v = (lane < 16) ? r[768 + lane] : 0.0f;
    unsigned long long m = __ballot((lane < 16) && (v == 1.0f));
    if (lane == 0) packed[(size_t)12 * BS_TOT + row] = m;
}

// 49-bit window of data bits starting at n0 (max a0+1 = 12, in bounds)
__device__ __forceinline__ unsigned long long bit_window(
        const unsigned long long* __restrict__ packed, int n0, int b) {
    int a0 = n0 >> 6, s = n0 & 63;
    unsigned long long w0 = packed[(size_t)a0 * BS_TOT + b];
    unsigned long long w1 = packed[(size_t)(a0 + 1) * BS_TOT + b];
    return s ? ((w0 >> s) | (w1 << (64 - s))) : w0;
}

// ================= kernel 2: per-segment 4x4 matrix products (R3-verified) =========
// LDS transposed to [site][phys][l][r]; selected matrix = 4x ds_read_b128.
// P_k = M_{kG} * ... * M_{kG+G-1} (row-vector). Pbuf: [k][b][r*4+j], k < KSEG-1 only.
__global__ __launch_bounds__(256) void phase1_kernel(const float* __restrict__ tensors,
                                                     const unsigned long long* __restrict__ packed,
                                                     float* __restrict__ Pbuf) {
    int b = blockIdx.x * 256 + threadIdx.x;
    int k = blockIdx.y;

    __shared__ __align__(16) float lt[GSEG * 32];        // [i][p][l][r]
    const float* g = tensors + (size_t)k * GSEG * 32;    // [i][l][r][p]
    for (int e = threadIdx.x; e < GSEG * 32; e += 256) {
        int i = e >> 5, rem = e & 31;
        int l = rem >> 3, r = (rem >> 1) & 3, p = rem & 1;
        lt[i * 32 + p * 16 + l * 4 + r] = g[e];
    }
    __syncthreads();

    unsigned long long win = bit_window(packed, k * GSEG, b);

    const float4* ms = (const float4*)&lt[(win & 1ull) ? 0 : 16];
    float4 P0 = ms[0], P1 = ms[1], P2 = ms[2], P3 = ms[3];

    #pragma unroll 3
    for (int i = 1; i < GSEG; ++i) {
        const float4* mi = (const float4*)&lt[i * 32 + (((win >> i) & 1ull) ? 0 : 16)];
        float4 m0 = mi[0], m1 = mi[1], m2 = mi[2], m3 = mi[3];
        float4 Q0, Q1, Q2, Q3;
        MM_ROW(Q0, P0); MM_ROW(Q1, P1); MM_ROW(Q2, P2); MM_ROW(Q3, P3);
        P0 = Q0; P1 = Q1; P2 = Q2; P3 = Q3;
    }

    float4* pb = (float4*)(Pbuf + ((size_t)k * BS_TOT + b) * 16);
    pb[0] = P0; pb[1] = P1; pb[2] = P2; pb[3] = P3;
}

// ================= kernel 3: fused prefix scan + log-softmax walk + reduce =========
// block = 512 thr = 8 waves, 64 samples; wave 0 scans, wave w walks segs {w, w+8}.
__global__ __launch_bounds__(512, 8) void scan_walk_kernel(
    const float* __restrict__ tensors,
    const unsigned long long* __restrict__ packed,
    const float* __restrict__ Pbuf,
    float* __restrict__ out)
{
    __shared__ float sPre[KSEG][4][WPB];   // prefix left vectors, [..][lane] conflict-free
    __shared__ float sRes[KSEG][WPB];      // per-segment partials

    const int t    = threadIdx.x;
    const int wv   = t >> 6;
    const int lane = t & 63;
    const int s0   = blockIdx.x * WPB;
    const int b    = s0 + lane;

    // ---------- phase B: wave 0 scans 15 segment products (R3 phase2 body) ----------
    if (wv == 0) {
        float l0 = 1.0f, l1 = 0.0f, l2 = 0.0f, l3 = 0.0f;
        const float4* base = (const float4*)Pbuf + (size_t)b * 4;
        #pragma unroll
        for (int k = 0; k < KSEG; ++k) {
            sPre[k][0][lane] = l0; sPre[k][1][lane] = l1;
            sPre[k][2][lane] = l2; sPre[k][3][lane] = l3;
            if (k < KSEG - 1) {
                const float4* pb = base + (size_t)k * BS_TOT * 4;
                float4 r0 = pb[0], r1 = pb[1], r2 = pb[2], r3 = pb[3];
                float n0 = fmaf(l0, r0.x, fmaf(l1, r1.x, fmaf(l2, r2.x, l3 * r3.x)));
                float n1 = fmaf(l0, r0.y, fmaf(l1, r1.y, fmaf(l2, r2.y, l3 * r3.y)));
                float n2 = fmaf(l0, r0.z, fmaf(l1, r1.z, fmaf(l2, r2.z, l3 * r3.z)));
                float n3 = fmaf(l0, r0.w, fmaf(l1, r1.w, fmaf(l2, r2.w, l3 * r3.w)));
                l0 = n0; l1 = n1; l2 = n2; l3 = n3;
            }
        }
    }
    __syncthreads();

    // ---------- phase C: each wave walks two segments (wave-uniform s_load tensors) ----
    #pragma unroll
    for (int rep = 0; rep < 2; ++rep) {
        const int k  = wv + rep * 8;
        const int n0 = k * GSEG;
        const float* tb = tensors + (size_t)n0 * 32;
        unsigned long long win = bit_window(packed, n0, b);

        float left0 = sPre[k][0][lane], left1 = sPre[k][1][lane];
        float left2 = sPre[k][2][lane], left3 = sPre[k][3][lane];
        float acc_nat = 0.0f, acc_l2 = 0.0f;
        #pragma unroll 7
        for (int i = 0; i < GSEG; ++i) {
            STEP(((win >> i) & 1ull) != 0, tb + i * 32);
        }
        sRes[k][lane] = acc_nat - 0.6931471805599453f * acc_l2;
    }
    __syncthreads();

    // ---------- phase D: reduce 16 partials per sample ----------
    if (wv == 0) {
        float acc = 0.0f;
        #pragma unroll
        for (int kk = 0; kk < KSEG; ++kk) acc += sRes[kk][lane];
        out[b] = acc;
    }
}

// ================= round-0 fallback (known-correct) =================
__global__ __launch_bounds__(64) void amps_chain_kernel(
    const float* __restrict__ data, const float* __restrict__ tensors,
    float* __restrict__ out)
{
    int b = blockIdx.x * blockDim.x + threadIdx.x;
    if (b >= BS_TOT) return;
    const float* row = data + (size_t)b * NSITES;
    float left0 = 1.0f, left1 = 0.0f, left2 = 0.0f, left3 = 0.0f;
    float acc_nat = 0.0f, acc_l2 = 0.0f;
    for (int n = 0; n < NSITES; ++n) {
        STEP(row[n] == 1.0f, tensors + (size_t)n * 32);
    }
    out[b] = acc_nat - 0.6931471805599453f * acc_l2;
}

extern "C" void kernel_launch(void* const* d_in, const int* in_sizes, int n_in,
                              void* d_out, int out_size, void* d_ws, size_t ws_size,
                              hipStream_t stream) {
    const float* data    = (const float*)d_in[0];   // (16384, 784) float32
    const float* tensors = (const float*)d_in[1];   // (784, 4, 4, 2) float32
    float* out = (float*)d_out;                     // (16384,) float32

    const size_t packed_bytes = (size_t)13 * BS_TOT * 8;                   //  1,703,936
    const size_t Pbuf_bytes   = (size_t)(KSEG - 1) * BS_TOT * 16 * 4;      // 15,728,640
    const size_t need = packed_bytes + Pbuf_bytes;

    if (ws_size < need) {
        hipLaunchKernelGGL(amps_chain_kernel, dim3(BS_TOT / 64), dim3(64), 0, stream,
                           data, tensors, out);
        return;
    }

    char* wsb = (char*)d_ws;
    unsigned long long* packed = (unsigned long long*)wsb;
    float* Pbuf = (float*)(wsb + packed_bytes);

    hipLaunchKernelGGL(pack_kernel,      dim3((BS_TOT * 64) / 256), dim3(256), 0, stream,
                       data, packed);
    hipLaunchKernelGGL(phase1_kernel,    dim3(BS_TOT / 256, KSEG - 1), dim3(256), 0, stream,
                       tensors, packed, Pbuf);
    hipLaunchKernelGGL(scan_walk_kernel, dim3(BS_TOT / WPB), dim3(512), 0, stream,
                       tensors, packed, Pbuf, out);
}

// Round 9
// 62.928 us; speedup vs baseline: 1.8386x; 1.4265x over previous
//
#include <hip/hip_runtime.h>

#define NSITES 784
#define BS_TOT 16384
#define KSEG 16
#define GSEG 49     // 16*49 = 784
#define WPB  64     // samples per scan_walk block (= lanes)

// ---------------- per-site step on 8 float4 regs (mapping verified R0/R5) ----------------
// c0..c7 = the 32 floats of site tensor, layout [l][r][p] flat l*8+r*2+p:
//   c{2l}   = (T[l][0][0], T[l][0][1], T[l][1][0], T[l][1][1])
//   c{2l+1} = (T[l][2][0], T[l][2][1], T[l][3][0], T[l][3][1])
#define STEP_REG(bitset, c0,c1,c2,c3,c4,c5,c6,c7) do { \
  float p00 = fmaf(left0, c0.x, fmaf(left1, c2.x, fmaf(left2, c4.x, left3 * c6.x))); \
  float p01 = fmaf(left0, c0.y, fmaf(left1, c2.y, fmaf(left2, c4.y, left3 * c6.y))); \
  float p10 = fmaf(left0, c0.z, fmaf(left1, c2.z, fmaf(left2, c4.z, left3 * c6.z))); \
  float p11 = fmaf(left0, c0.w, fmaf(left1, c2.w, fmaf(left2, c4.w, left3 * c6.w))); \
  float p20 = fmaf(left0, c1.x, fmaf(left1, c3.x, fmaf(left2, c5.x, left3 * c7.x))); \
  float p21 = fmaf(left0, c1.y, fmaf(left1, c3.y, fmaf(left2, c5.y, left3 * c7.y))); \
  float p30 = fmaf(left0, c1.z, fmaf(left1, c3.z, fmaf(left2, c5.z, left3 * c7.z))); \
  float p31 = fmaf(left0, c1.w, fmaf(left1, c3.w, fmaf(left2, c5.w, left3 * c7.w))); \
  bool s_ = (bitset); \
  float mx_ = fmaxf(p00, p01); \
  float ch_ = s_ ? p00 : p01; \
  acc_nat += (ch_ - mx_); \
  float ad_ = fabsf(p00 - p01); \
  acc_l2 += __builtin_amdgcn_logf(1.0f + __builtin_amdgcn_exp2f(-ad_ * 1.4426950408889634f)); \
  left0 = s_ ? p00 : p01; \
  left1 = s_ ? p10 : p11; \
  left2 = s_ ? p20 : p21; \
  left3 = s_ ? p30 : p31; \
} while (0)

// scalar-pointer STEP (round-0 verified) -- used by fallback only
#define STEP(sbit, TP) do {                                                          \
    const float* t_ = (TP);                                                          \
    float p00 = fmaf(left0, t_[0],  fmaf(left1, t_[8],  fmaf(left2, t_[16], left3 * t_[24]))); \
    float p01 = fmaf(left0, t_[1],  fmaf(left1, t_[9],  fmaf(left2, t_[17], left3 * t_[25]))); \
    float p10 = fmaf(left0, t_[2],  fmaf(left1, t_[10], fmaf(left2, t_[18], left3 * t_[26]))); \
    float p11 = fmaf(left0, t_[3],  fmaf(left1, t_[11], fmaf(left2, t_[19], left3 * t_[27]))); \
    float p20 = fmaf(left0, t_[4],  fmaf(left1, t_[12], fmaf(left2, t_[20], left3 * t_[28]))); \
    float p21 = fmaf(left0, t_[5],  fmaf(left1, t_[13], fmaf(left2, t_[21], left3 * t_[29]))); \
    float p30 = fmaf(left0, t_[6],  fmaf(left1, t_[14], fmaf(left2, t_[22], left3 * t_[30]))); \
    float p31 = fmaf(left0, t_[7],  fmaf(left1, t_[15], fmaf(left2, t_[23], left3 * t_[31]))); \
    bool s_ = (sbit);                                                                \
    float mx_ = fmaxf(p00, p01);                                                     \
    float ch_ = s_ ? p00 : p01;                                                      \
    acc_nat += (ch_ - mx_);                                                          \
    float ad_ = fabsf(p00 - p01);                                                    \
    acc_l2 += __builtin_amdgcn_logf(1.0f + __builtin_amdgcn_exp2f(-ad_ * 1.4426950408889634f)); \
    left0 = s_ ? p00 : p01;                                                          \
    left1 = s_ ? p10 : p11;                                                          \
    left2 = s_ ? p20 : p21;                                                          \
    left3 = s_ ? p30 : p31;                                                          \
} while (0)

// Q_row = P_row * M  (rows of M in float4 m0..m3)
#define MM_ROW(Q, Pr) do {                                                           \
    Q.x = fmaf(Pr.x, m0.x, fmaf(Pr.y, m1.x, fmaf(Pr.z, m2.x, Pr.w * m3.x)));         \
    Q.y = fmaf(Pr.x, m0.y, fmaf(Pr.y, m1.y, fmaf(Pr.z, m2.y, Pr.w * m3.y)));         \
    Q.z = fmaf(Pr.x, m0.z, fmaf(Pr.y, m1.z, fmaf(Pr.z, m2.z, Pr.w * m3.z)));         \
    Q.w = fmaf(Pr.x, m0.w, fmaf(Pr.y, m1.w, fmaf(Pr.z, m2.w, Pr.w * m3.w)));         \
} while (0)

// ================= kernel 1: pack data bits (coalesced + ballot) =================
__global__ __launch_bounds__(256) void pack_kernel(const float* __restrict__ data,
                                                   unsigned long long* __restrict__ packed) {
    int gid  = blockIdx.x * 256 + threadIdx.x;
    int row  = gid >> 6;
    int lane = threadIdx.x & 63;
    const float* r = data + (size_t)row * NSITES;
    #pragma unroll
    for (int w = 0; w < 12; ++w) {
        unsigned long long m = __ballot(r[w * 64 + lane] == 1.0f);
        if (lane == 0) packed[(size_t)w * BS_TOT + row] = m;
    }
    float v = (lane < 16) ? r[768 + lane] : 0.0f;
    unsigned long long m = __ballot((lane < 16) && (v == 1.0f));
    if (lane == 0) packed[(size_t)12 * BS_TOT + row] = m;
}

// 49-bit window of data bits starting at n0 (max word index 12, in bounds)
__device__ __forceinline__ unsigned long long bit_window(
        const unsigned long long* __restrict__ packed, int n0, int b) {
    int a0 = n0 >> 6, s = n0 & 63;
    unsigned long long w0 = packed[(size_t)a0 * BS_TOT + b];
    unsigned long long w1 = packed[(size_t)(a0 + 1) * BS_TOT + b];
    return s ? ((w0 >> s) | (w1 << (64 - s))) : w0;
}

// ================= kernel 2: per-segment 4x4 matrix products (R3-verified) =========
__global__ __launch_bounds__(256) void phase1_kernel(const float* __restrict__ tensors,
                                                     const unsigned long long* __restrict__ packed,
                                                     float* __restrict__ Pbuf) {
    int b = blockIdx.x * 256 + threadIdx.x;
    int k = blockIdx.y;

    __shared__ __align__(16) float lt[GSEG * 32];        // [i][p][l][r]
    const float* g = tensors + (size_t)k * GSEG * 32;    // [i][l][r][p]
    for (int e = threadIdx.x; e < GSEG * 32; e += 256) {
        int i = e >> 5, rem = e & 31;
        int l = rem >> 3, r = (rem >> 1) & 3, p = rem & 1;
        lt[i * 32 + p * 16 + l * 4 + r] = g[e];
    }
    __syncthreads();

    unsigned long long win = bit_window(packed, k * GSEG, b);

    const float4* ms = (const float4*)&lt[(win & 1ull) ? 0 : 16];
    float4 P0 = ms[0], P1 = ms[1], P2 = ms[2], P3 = ms[3];

    #pragma unroll 3
    for (int i = 1; i < GSEG; ++i) {
        const float4* mi = (const float4*)&lt[i * 32 + (((win >> i) & 1ull) ? 0 : 16)];
        float4 m0 = mi[0], m1 = mi[1], m2 = mi[2], m3 = mi[3];
        float4 Q0, Q1, Q2, Q3;
        MM_ROW(Q0, P0); MM_ROW(Q1, P1); MM_ROW(Q2, P2); MM_ROW(Q3, P3);
        P0 = Q0; P1 = Q1; P2 = Q2; P3 = Q3;
    }

    float4* pb = (float4*)(Pbuf + ((size_t)k * BS_TOT + b) * 16);
    pb[0] = P0; pb[1] = P1; pb[2] = P2; pb[3] = P3;
}

// ================= kernel 3: fused scan + walk + reduce, tensors in LDS =========
// block = 1024 thr = 16 waves, 64 samples; wave w walks segment w from LDS broadcast.
__global__ __launch_bounds__(1024, 4) void scan_walk_kernel(
    const float* __restrict__ tensors,
    const unsigned long long* __restrict__ packed,
    const float* __restrict__ Pbuf,
    float* __restrict__ out)
{
    __shared__ __align__(16) float lt[NSITES * 32];   // 98 KB: ALL site tensors
    __shared__ float sPre[KSEG][4][WPB];              // 16 KB prefix left vectors
    __shared__ float sRes[KSEG][WPB];                 // 4 KB partials

    const int t    = threadIdx.x;
    const int wv   = t >> 6;
    const int lane = t & 63;
    const int s0   = blockIdx.x * WPB;
    const int b    = s0 + lane;

    // ---------- stage all tensors -> LDS (coalesced float4) ----------
    {
        const float4* src = (const float4*)tensors;
        float4* dst = (float4*)lt;
        #pragma unroll
        for (int e = t; e < NSITES * 8; e += 1024) dst[e] = src[e];
    }

    // ---------- phase B: wave 0 scans 15 segment products (chunked loads) ----------
    if (wv == 0) {
        float l0 = 1.0f, l1 = 0.0f, l2 = 0.0f, l3 = 0.0f;
        const float4* base = (const float4*)Pbuf + (size_t)b * 4;
        #pragma unroll
        for (int kc = 0; kc < 3; ++kc) {              // 3 chunks of 5 segments
            float4 R[5][4];
            #pragma unroll
            for (int j = 0; j < 5; ++j) {
                const float4* pb = base + (size_t)(kc * 5 + j) * BS_TOT * 4;
                R[j][0] = pb[0]; R[j][1] = pb[1]; R[j][2] = pb[2]; R[j][3] = pb[3];
            }
            #pragma unroll
            for (int j = 0; j < 5; ++j) {
                const int k = kc * 5 + j;
                sPre[k][0][lane] = l0; sPre[k][1][lane] = l1;
                sPre[k][2][lane] = l2; sPre[k][3][lane] = l3;
                float n0 = fmaf(l0, R[j][0].x, fmaf(l1, R[j][1].x, fmaf(l2, R[j][2].x, l3 * R[j][3].x)));
                float n1 = fmaf(l0, R[j][0].y, fmaf(l1, R[j][1].y, fmaf(l2, R[j][2].y, l3 * R[j][3].y)));
                float n2 = fmaf(l0, R[j][0].z, fmaf(l1, R[j][1].z, fmaf(l2, R[j][2].z, l3 * R[j][3].z)));
                float n3 = fmaf(l0, R[j][0].w, fmaf(l1, R[j][1].w, fmaf(l2, R[j][2].w, l3 * R[j][3].w)));
                l0 = n0; l1 = n1; l2 = n2; l3 = n3;
            }
        }
        sPre[15][0][lane] = l0; sPre[15][1][lane] = l1;
        sPre[15][2][lane] = l2; sPre[15][3][lane] = l3;
    }
    __syncthreads();

    // ---------- phase C: wave w walks segment w (LDS broadcast reads) ----------
    {
        const int k  = wv;
        const int n0 = k * GSEG;
        unsigned long long win = bit_window(packed, n0, b);

        float left0 = sPre[k][0][lane], left1 = sPre[k][1][lane];
        float left2 = sPre[k][2][lane], left3 = sPre[k][3][lane];
        float acc_nat = 0.0f, acc_l2 = 0.0f;

        const float4* tseg = (const float4*)&lt[n0 * 32];
        #pragma unroll 7
        for (int i = 0; i < GSEG; ++i) {
            float4 c0 = tseg[i * 8 + 0], c1 = tseg[i * 8 + 1];
            float4 c2 = tseg[i * 8 + 2], c3 = tseg[i * 8 + 3];
            float4 c4 = tseg[i * 8 + 4], c5 = tseg[i * 8 + 5];
            float4 c6 = tseg[i * 8 + 6], c7 = tseg[i * 8 + 7];
            STEP_REG(((win >> i) & 1ull) != 0, c0,c1,c2,c3,c4,c5,c6,c7);
        }
        sRes[k][lane] = acc_nat - 0.6931471805599453f * acc_l2;
    }
    __syncthreads();

    // ---------- phase D: reduce 16 partials per sample ----------
    if (wv == 0) {
        float acc = 0.0f;
        #pragma unroll
        for (int kk = 0; kk < KSEG; ++kk) acc += sRes[kk][lane];
        out[b] = acc;
    }
}

// ================= round-0 fallback (known-correct) =================
__global__ __launch_bounds__(64) void amps_chain_kernel(
    const float* __restrict__ data, const float* __restrict__ tensors,
    float* __restrict__ out)
{
    int b = blockIdx.x * blockDim.x + threadIdx.x;
    if (b >= BS_TOT) return;
    const float* row = data + (size_t)b * NSITES;
    float left0 = 1.0f, left1 = 0.0f, left2 = 0.0f, left3 = 0.0f;
    float acc_nat = 0.0f, acc_l2 = 0.0f;
    for (int n = 0; n < NSITES; ++n) {
        STEP(row[n] == 1.0f, tensors + (size_t)n * 32);
    }
    out[b] = acc_nat - 0.6931471805599453f * acc_l2;
}

extern "C" void kernel_launch(void* const* d_in, const int* in_sizes, int n_in,
                              void* d_out, int out_size, void* d_ws, size_t ws_size,
                              hipStream_t stream) {
    const float* data    = (const float*)d_in[0];   // (16384, 784) float32
    const float* tensors = (const float*)d_in[1];   // (784, 4, 4, 2) float32
    float* out = (float*)d_out;                     // (16384,) float32

    const size_t packed_bytes = (size_t)13 * BS_TOT * 8;                   //  1,703,936
    const size_t Pbuf_bytes   = (size_t)(KSEG - 1) * BS_TOT * 16 * 4;      // 15,728,640
    const size_t need = packed_bytes + Pbuf_bytes;

    if (ws_size < need) {
        hipLaunchKernelGGL(amps_chain_kernel, dim3(BS_TOT / 64), dim3(64), 0, stream,
                           data, tensors, out);
        return;
    }

    char* wsb = (char*)d_ws;
    unsigned long long* packed = (unsigned long long*)wsb;
    float* Pbuf = (float*)(wsb + packed_bytes);

    hipLaunchKernelGGL(pack_kernel,      dim3((BS_TOT * 64) / 256), dim3(256), 0, stream,
                       data, packed);
    hipLaunchKernelGGL(phase1_kernel,    dim3(BS_TOT / 256, KSEG - 1), dim3(256), 0, stream,
                       tensors, packed, Pbuf);
    hipLaunchKernelGGL(scan_walk_kernel, dim3(BS_TOT / WPB), dim3(1024), 0, stream,
                       tensors, packed, Pbuf, out);
}

// Round 10
// 55.963 us; speedup vs baseline: 2.0674x; 1.1244x over previous
//
#include <hip/hip_runtime.h>

#define NSITES 784
#define BS_TOT 16384
#define KSEG 16
#define GSEG 49     // 16*49 = 784; 49 = 12 quads * 4 + 1 site
#define NQUAD 12
#define WPB  64     // samples per scan_walk block (= lanes)

typedef unsigned long long u64;

// ---------------- per-site step (round-0 verified, absmax 0) ----------------
// t_ -> site tensor (32 floats, layout [l][r][p], flat l*8+r*2+p). Uniform -> s_load.
#define STEP(sbit, TP) do {                                                          \
    const float* t_ = (TP);                                                          \
    float p00 = fmaf(left0, t_[0],  fmaf(left1, t_[8],  fmaf(left2, t_[16], left3 * t_[24]))); \
    float p01 = fmaf(left0, t_[1],  fmaf(left1, t_[9],  fmaf(left2, t_[17], left3 * t_[25]))); \
    float p10 = fmaf(left0, t_[2],  fmaf(left1, t_[10], fmaf(left2, t_[18], left3 * t_[26]))); \
    float p11 = fmaf(left0, t_[3],  fmaf(left1, t_[11], fmaf(left2, t_[19], left3 * t_[27]))); \
    float p20 = fmaf(left0, t_[4],  fmaf(left1, t_[12], fmaf(left2, t_[20], left3 * t_[28]))); \
    float p21 = fmaf(left0, t_[5],  fmaf(left1, t_[13], fmaf(left2, t_[21], left3 * t_[29]))); \
    float p30 = fmaf(left0, t_[6],  fmaf(left1, t_[14], fmaf(left2, t_[22], left3 * t_[30]))); \
    float p31 = fmaf(left0, t_[7],  fmaf(left1, t_[15], fmaf(left2, t_[23], left3 * t_[31]))); \
    bool s_ = (sbit);                                                                \
    float mx_ = fmaxf(p00, p01);                                                     \
    float ch_ = s_ ? p00 : p01;                                                      \
    acc_nat += (ch_ - mx_);                                                          \
    float ad_ = fabsf(p00 - p01);                                                    \
    acc_l2 += __builtin_amdgcn_logf(1.0f + __builtin_amdgcn_exp2f(-ad_ * 1.4426950408889634f)); \
    left0 = s_ ? p00 : p01;                                                          \
    left1 = s_ ? p10 : p11;                                                          \
    left2 = s_ ? p20 : p21;                                                          \
    left3 = s_ ? p30 : p31;                                                          \
} while (0)

// Q_row = P_row * M  (rows of M in float4 m0..m3)
#define MM_ROW(Q, Pr) do {                                                           \
    Q.x = fmaf(Pr.x, m0.x, fmaf(Pr.y, m1.x, fmaf(Pr.z, m2.x, Pr.w * m3.x)));         \
    Q.y = fmaf(Pr.x, m0.y, fmaf(Pr.y, m1.y, fmaf(Pr.z, m2.y, Pr.w * m3.y)));         \
    Q.z = fmaf(Pr.x, m0.z, fmaf(Pr.y, m1.z, fmaf(Pr.z, m2.z, Pr.w * m3.z)));         \
    Q.w = fmaf(Pr.x, m0.w, fmaf(Pr.y, m1.w, fmaf(Pr.z, m2.w, Pr.w * m3.w)));         \
} while (0)

#define MM4(P0,P1,P2,P3) do { float4 Q0,Q1,Q2,Q3; \
    MM_ROW(Q0,P0); MM_ROW(Q1,P1); MM_ROW(Q2,P2); MM_ROW(Q3,P3); \
    P0=Q0; P1=Q1; P2=Q2; P3=Q3; } while (0)

// ================= kernel 0: precompute quad products (data-independent) =========
// QQ[k*12+q][c][a*4+b] = (M_{n0+4q}^{b0} M_{n0+4q+1}^{b1} M_{n0+4q+2}^{b2} M_{n0+4q+3}^{b3})[a][b]
// c = b0 | b1<<1 | b2<<2 | b3<<3; bit=1 -> x=1 -> phys 0. Row-vector convention.
__global__ __launch_bounds__(256) void pp_qq_kernel(const float* __restrict__ tensors,
                                                    float* __restrict__ QQ) {
    __shared__ float sPP[24][4][16];   // pair products for this segment
    const int k = blockIdx.x;          // segment
    const int t = threadIdx.x;
    const int n0 = k * GSEG;

    if (t < 96) {                      // 24 pairs x 4 combos
        const int j = t >> 2, c2 = t & 3;
        const float* t0 = tensors + (size_t)(n0 + 2 * j) * 32;
        const float* t1 = tensors + (size_t)(n0 + 2 * j + 1) * 32;
        const int p0 = (c2 & 1) ? 0 : 1;
        const int p1 = (c2 & 2) ? 0 : 1;
        float A[4][4], B[4][4];
        #pragma unroll
        for (int l = 0; l < 4; ++l)
            #pragma unroll
            for (int r = 0; r < 4; ++r) {
                A[l][r] = t0[l * 8 + r * 2 + p0];
                B[l][r] = t1[l * 8 + r * 2 + p1];
            }
        #pragma unroll
        for (int a = 0; a < 4; ++a)
            #pragma unroll
            for (int bb = 0; bb < 4; ++bb)
                sPP[j][c2][a * 4 + bb] =
                    fmaf(A[a][0], B[0][bb], fmaf(A[a][1], B[1][bb],
                    fmaf(A[a][2], B[2][bb], A[a][3] * B[3][bb])));
    }
    __syncthreads();

    if (t < 192) {                     // 12 quads x 16 combos
        const int q = t >> 4, c = t & 15;
        const float* A = sPP[2 * q][c & 3];
        const float* B = sPP[2 * q + 1][(c >> 2) & 3];
        float* dst = QQ + ((size_t)(k * NQUAD + q) * 16 + c) * 16;
        #pragma unroll
        for (int a = 0; a < 4; ++a)
            #pragma unroll
            for (int bb = 0; bb < 4; ++bb)
                dst[a * 4 + bb] =
                    fmaf(A[a * 4 + 0], B[0 * 4 + bb], fmaf(A[a * 4 + 1], B[1 * 4 + bb],
                    fmaf(A[a * 4 + 2], B[2 * 4 + bb], A[a * 4 + 3] * B[3 * 4 + bb])));
    }
}

// ================= kernel 1: pack data bits (coalesced + ballot) =================
__global__ __launch_bounds__(256) void pack_kernel(const float* __restrict__ data,
                                                   u64* __restrict__ packed) {
    int gid  = blockIdx.x * 256 + threadIdx.x;
    int row  = gid >> 6;
    int lane = threadIdx.x & 63;
    const float* r = data + (size_t)row * NSITES;
    #pragma unroll
    for (int w = 0; w < 12; ++w) {
        u64 m = __ballot(r[w * 64 + lane] == 1.0f);
        if (lane == 0) packed[(size_t)w * BS_TOT + row] = m;
    }
    float v = (lane < 16) ? r[768 + lane] : 0.0f;
    u64 m = __ballot((lane < 16) && (v == 1.0f));
    if (lane == 0) packed[(size_t)12 * BS_TOT + row] = m;
}

// 49-bit window of data bits starting at n0 (max word index 12, in bounds)
__device__ __forceinline__ u64 bit_window(const u64* __restrict__ packed, int n0, int b) {
    int a0 = n0 >> 6, s = n0 & 63;
    u64 w0 = packed[(size_t)a0 * BS_TOT + b];
    u64 w1 = packed[(size_t)(a0 + 1) * BS_TOT + b];
    return s ? ((w0 >> s) | (w1 << (64 - s))) : w0;
}

// ================= kernel 2: per-segment products from quads =================
// P_k = QQ_0 * QQ_1 * ... * QQ_11 * M_{n0+48}.  Pbuf: [k][b][a*4+j], k < KSEG-1.
// LDS: [12][16][20] floats (combo stride 20 -> 2-way bank alias = free, 16B aligned)
__global__ __launch_bounds__(256) void phase1q_kernel(const float* __restrict__ tensors,
                                                      const u64* __restrict__ packed,
                                                      const float* __restrict__ QQ,
                                                      float* __restrict__ Pbuf) {
    const int b = blockIdx.x * 256 + threadIdx.x;
    const int k = blockIdx.y;
    const int n0 = k * GSEG;

    __shared__ __align__(16) float lt[NQUAD * 16 * 20];
    {
        const float4* src = (const float4*)(QQ + (size_t)k * NQUAD * 16 * 16);
        float4* dst = (float4*)lt;
        for (int e = threadIdx.x; e < NQUAD * 16 * 4; e += 256) {  // 768 float4s
            int q = e >> 6, c = (e >> 2) & 15, j = e & 3;
            dst[q * 80 + c * 5 + j] = src[e];
        }
    }
    __syncthreads();

    u64 win = bit_window(packed, n0, b);
    const float4* ltf4 = (const float4*)lt;

    // quad 0 initializes P
    float4 P0, P1, P2, P3;
    {
        const int c0 = (int)(win & 15ull);
        const float4* mi = ltf4 + (c0 * 5);
        P0 = mi[0]; P1 = mi[1]; P2 = mi[2]; P3 = mi[3];
    }
    #pragma unroll
    for (int q = 1; q < NQUAD; ++q) {
        const int cq = (int)((win >> (4 * q)) & 15ull);
        const float4* mi = ltf4 + (q * 80 + cq * 5);
        float4 m0 = mi[0], m1 = mi[1], m2 = mi[2], m3 = mi[3];
        MM4(P0, P1, P2, P3);
    }
    // final single site n0+48: block-uniform tensor -> s_load; per-lane phys select
    {
        const float* t48 = tensors + (size_t)(n0 + 48) * 32;
        const bool s48 = ((win >> 48) & 1ull) != 0;
        float4 m0 = make_float4(s48 ? t48[0]  : t48[1],  s48 ? t48[2]  : t48[3],
                                s48 ? t48[4]  : t48[5],  s48 ? t48[6]  : t48[7]);
        float4 m1 = make_float4(s48 ? t48[8]  : t48[9],  s48 ? t48[10] : t48[11],
                                s48 ? t48[12] : t48[13], s48 ? t48[14] : t48[15]);
        float4 m2 = make_float4(s48 ? t48[16] : t48[17], s48 ? t48[18] : t48[19],
                                s48 ? t48[20] : t48[21], s48 ? t48[22] : t48[23]);
        float4 m3 = make_float4(s48 ? t48[24] : t48[25], s48 ? t48[26] : t48[27],
                                s48 ? t48[28] : t48[29], s48 ? t48[30] : t48[31]);
        MM4(P0, P1, P2, P3);
    }

    float4* pb = (float4*)(Pbuf + ((size_t)k * BS_TOT + b) * 16);
    pb[0] = P0; pb[1] = P1; pb[2] = P2; pb[3] = P3;
}

// ================= kernel 3: fused scan + walk + reduce (s_load tensors) =========
// block = 1024 thr = 16 waves, 64 samples; wave w walks segment w via scalar loads.
__global__ __launch_bounds__(1024, 4) void scan_walk_kernel(
    const float* __restrict__ tensors,
    const u64* __restrict__ packed,
    const float* __restrict__ Pbuf,
    float* __restrict__ out)
{
    __shared__ float sPre[KSEG][4][WPB];   // prefix left vectors, [..][lane] conflict-free
    __shared__ float sRes[KSEG][WPB];      // per-segment partials

    const int t    = threadIdx.x;
    const int wv   = t >> 6;
    const int lane = t & 63;
    const int s0   = blockIdx.x * WPB;
    const int b    = s0 + lane;

    // ---------- phase B: wave 0 scans 15 segment products (chunked loads) ----------
    if (wv == 0) {
        float l0 = 1.0f, l1 = 0.0f, l2 = 0.0f, l3 = 0.0f;
        const float4* base = (const float4*)Pbuf + (size_t)b * 4;
        #pragma unroll
        for (int kc = 0; kc < 3; ++kc) {              // 3 chunks of 5 segments
            float4 R[5][4];
            #pragma unroll
            for (int j = 0; j < 5; ++j) {
                const float4* pb = base + (size_t)(kc * 5 + j) * BS_TOT * 4;
                R[j][0] = pb[0]; R[j][1] = pb[1]; R[j][2] = pb[2]; R[j][3] = pb[3];
            }
            #pragma unroll
            for (int j = 0; j < 5; ++j) {
                const int k = kc * 5 + j;
                sPre[k][0][lane] = l0; sPre[k][1][lane] = l1;
                sPre[k][2][lane] = l2; sPre[k][3][lane] = l3;
                float n0 = fmaf(l0, R[j][0].x, fmaf(l1, R[j][1].x, fmaf(l2, R[j][2].x, l3 * R[j][3].x)));
                float n1 = fmaf(l0, R[j][0].y, fmaf(l1, R[j][1].y, fmaf(l2, R[j][2].y, l3 * R[j][3].y)));
                float n2 = fmaf(l0, R[j][0].z, fmaf(l1, R[j][1].z, fmaf(l2, R[j][2].z, l3 * R[j][3].z)));
                float n3 = fmaf(l0, R[j][0].w, fmaf(l1, R[j][1].w, fmaf(l2, R[j][2].w, l3 * R[j][3].w)));
                l0 = n0; l1 = n1; l2 = n2; l3 = n3;
            }
        }
        sPre[15][0][lane] = l0; sPre[15][1][lane] = l1;
        sPre[15][2][lane] = l2; sPre[15][3][lane] = l3;
    }
    __syncthreads();

    // ---------- phase C: wave w walks segment w (scalar s_load tensors) ----------
    {
        const int k  = wv;
        const int n0 = k * GSEG;
        u64 win = bit_window(packed, n0, b);

        // readfirstlane -> provably wave-uniform base -> s_load_dwordx16 path
        const int n0u = __builtin_amdgcn_readfirstlane(n0);
        const float* tb = tensors + (size_t)n0u * 32;

        float left0 = sPre[k][0][lane], left1 = sPre[k][1][lane];
        float left2 = sPre[k][2][lane], left3 = sPre[k][3][lane];
        float acc_nat = 0.0f, acc_l2 = 0.0f;
        #pragma unroll 7
        for (int i = 0; i < GSEG; ++i) {
            STEP(((win >> i) & 1ull) != 0, tb + i * 32);
        }
        sRes[k][lane] = acc_nat - 0.6931471805599453f * acc_l2;
    }
    __syncthreads();

    // ---------- phase D: reduce 16 partials per sample ----------
    if (wv == 0) {
        float acc = 0.0f;
        #pragma unroll
        for (int kk = 0; kk < KSEG; ++kk) acc += sRes[kk][lane];
        out[b] = acc;
    }
}

// ================= round-0 fallback (known-correct) =================
__global__ __launch_bounds__(64) void amps_chain_kernel(
    const float* __restrict__ data, const float* __restrict__ tensors,
    float* __restrict__ out)
{
    int b = blockIdx.x * blockDim.x + threadIdx.x;
    if (b >= BS_TOT) return;
    const float* row = data + (size_t)b * NSITES;
    float left0 = 1.0f, left1 = 0.0f, left2 = 0.0f, left3 = 0.0f;
    float acc_nat = 0.0f, acc_l2 = 0.0f;
    for (int n = 0; n < NSITES; ++n) {
        STEP(row[n] == 1.0f, tensors + (size_t)n * 32);
    }
    out[b] = acc_nat - 0.6931471805599453f * acc_l2;
}

extern "C" void kernel_launch(void* const* d_in, const int* in_sizes, int n_in,
                              void* d_out, int out_size, void* d_ws, size_t ws_size,
                              hipStream_t stream) {
    const float* data    = (const float*)d_in[0];   // (16384, 784) float32
    const float* tensors = (const float*)d_in[1];   // (784, 4, 4, 2) float32
    float* out = (float*)d_out;                     // (16384,) float32

    const size_t packed_bytes = (size_t)13 * BS_TOT * 8;                   //  1,703,936
    const size_t Pbuf_bytes   = (size_t)(KSEG - 1) * BS_TOT * 16 * 4;      // 15,728,640
    const size_t QQ_bytes     = (size_t)KSEG * NQUAD * 16 * 16 * 4;        //    786,432
    const size_t need = packed_bytes + Pbuf_bytes + QQ_bytes;

    if (ws_size < need) {
        hipLaunchKernelGGL(amps_chain_kernel, dim3(BS_TOT / 64), dim3(64), 0, stream,
                           data, tensors, out);
        return;
    }

    char* wsb = (char*)d_ws;
    u64*   packed = (u64*)wsb;
    float* Pbuf   = (float*)(wsb + packed_bytes);
    float* QQ     = (float*)(wsb + packed_bytes + Pbuf_bytes);

    hipLaunchKernelGGL(pp_qq_kernel,     dim3(KSEG), dim3(256), 0, stream, tensors, QQ);
    hipLaunchKernelGGL(pack_kernel,      dim3((BS_TOT * 64) / 256), dim3(256), 0, stream,
                       data, packed);
    hipLaunchKernelGGL(phase1q_kernel,   dim3(BS_TOT / 256, KSEG - 1), dim3(256), 0, stream,
                       tensors, packed, QQ, Pbuf);
    hipLaunchKernelGGL(scan_walk_kernel, dim3(BS_TOT / WPB), dim3(1024), 0, stream,
                       tensors, packed, Pbuf, out);
}